// Round 5
// baseline (466.260 us; speedup 1.0000x reference)
//
#include <hip/hip_runtime.h>
#include <hip/hip_fp16.h>

#define NEG 0.2f

typedef _Float16 f16x8 __attribute__((ext_vector_type(8)));
typedef _Float16 f16x2 __attribute__((ext_vector_type(2)));
typedef float    f32x4 __attribute__((ext_vector_type(4)));

__device__ __forceinline__ float fdot2h(__half2 a, __half2 b, float c) {
    return __builtin_amdgcn_fdot2(__builtin_bit_cast(f16x2, a),
                                  __builtin_bit_cast(f16x2, b), c, false);
}

__device__ __forceinline__ __half2 u2h2(unsigned int u) {
    return __builtin_bit_cast(__half2, u);
}

// packed half2 max via v_pk_max_f16 (ROCm header lacks __hmax2 on this toolchain)
__device__ __forceinline__ __half2 hmax2(__half2 a, __half2 b) {
    unsigned int ua = __builtin_bit_cast(unsigned int, a);
    unsigned int ub = __builtin_bit_cast(unsigned int, b);
    unsigned int ud;
    asm("v_pk_max_f16 %0, %1, %2" : "=v"(ud) : "v"(ua), "v"(ub));
    return __builtin_bit_cast(__half2, ud);
}

// ---- DPP cross-lane add via compiler intrinsic (hazards handled by compiler).
// CTRL: 0xB1 = quad_perm[1,0,3,2] (lane^1), 0x4E = quad_perm[2,3,0,1] (lane^2),
//       0x141 = row_half_mirror (==xor4 after the xor1,xor2 stages).
template<int CTRL>
__device__ __forceinline__ float dppadd(float x) {
    int xi = __builtin_bit_cast(int, x);
    int yi = __builtin_amdgcn_update_dpp(0, xi, CTRL, 0xf, 0xf, true);
    return x + __builtin_bit_cast(float, yi);
}

// ---------------- MFMA GEMM: Y = half(X[N,128] @ [Wl|Wr] + bias) ----------------
// HPL: write YL head-pair-major as [2][N][64] (for the head-split fused layer-1).
template<int CPW, bool IN_F16, bool HPL>
__global__ __launch_bounds__(256) void mfma_gemm_k(
    const float* __restrict__ Xf, const __half* __restrict__ Xh,
    const float* __restrict__ Wl, const float* __restrict__ bl,
    const float* __restrict__ Wr, const float* __restrict__ br,
    __half* __restrict__ YL, __half* __restrict__ YR, int nrows)
{
    __shared__ _Float16 Xs[128 * 136];
    __shared__ _Float16 Ws[128 * 136];

    const int t    = threadIdx.x;
    const int row0 = blockIdx.x * 128;
    const int c0   = blockIdx.y * 128;

    if constexpr (IN_F16) {
        for (int i = t; i < 128 * 16; i += 256) {
            int r = i >> 4, c = i & 15;
            int gr = row0 + r;
            uint4 v = make_uint4(0u, 0u, 0u, 0u);
            if (gr < nrows) v = ((const uint4*)Xh)[(long)gr * 16 + c];
            *(uint4*)&Xs[r * 136 + c * 8] = v;
        }
    } else {
        for (int i = t; i < 128 * 16; i += 256) {
            int r = i >> 4, c = i & 15;
            int gr = row0 + r;
            float4 a = make_float4(0.f,0.f,0.f,0.f), b4 = make_float4(0.f,0.f,0.f,0.f);
            if (gr < nrows) {
                a  = ((const float4*)Xf)[(long)gr * 32 + c * 2];
                b4 = ((const float4*)Xf)[(long)gr * 32 + c * 2 + 1];
            }
            _Float16 h[8] = {(_Float16)a.x,(_Float16)a.y,(_Float16)a.z,(_Float16)a.w,
                             (_Float16)b4.x,(_Float16)b4.y,(_Float16)b4.z,(_Float16)b4.w};
            *(f16x8*)&Xs[r * 136 + c * 8] = *(f16x8*)h;
        }
    }

    for (int i = t; i < 128 * 128; i += 256) {
        int k = i >> 7, n = i & 127;
        int gc = c0 + n;
        const float* Wp = (gc >= CPW) ? Wr : Wl;
        int lc = gc & (CPW - 1);
        Ws[n * 136 + k] = (_Float16)Wp[(long)k * CPW + lc];
    }
    __syncthreads();

    const int lane  = t & 63;
    const int wv    = t >> 6;
    const int m     = lane & 15;
    const int quad  = lane >> 4;
    const int rbase = wv * 32;

    f16x8 Af[2][4];
    #pragma unroll
    for (int rt = 0; rt < 2; ++rt)
        #pragma unroll
        for (int ks = 0; ks < 4; ++ks)
            Af[rt][ks] = *(const f16x8*)&Xs[(rbase + rt * 16 + m) * 136 + ks * 32 + quad * 8];

    f32x4 acc[2][8];
    #pragma unroll
    for (int rt = 0; rt < 2; ++rt)
        #pragma unroll
        for (int ct = 0; ct < 8; ++ct)
            acc[rt][ct] = (f32x4){0.f, 0.f, 0.f, 0.f};

    #pragma unroll
    for (int ct = 0; ct < 8; ++ct) {
        #pragma unroll
        for (int ks = 0; ks < 4; ++ks) {
            f16x8 Bf = *(const f16x8*)&Ws[(ct * 16 + m) * 136 + ks * 32 + quad * 8];
            acc[0][ct] = __builtin_amdgcn_mfma_f32_16x16x32_f16(Af[0][ks], Bf, acc[0][ct], 0, 0, 0);
            acc[1][ct] = __builtin_amdgcn_mfma_f32_16x16x32_f16(Af[1][ks], Bf, acc[1][ct], 0, 0, 0);
        }
    }

    #pragma unroll
    for (int ct = 0; ct < 8; ++ct) {
        int gc = c0 + ct * 16 + m;
        int which = gc / CPW;
        int lc = gc % CPW;
        _Float16* Y = (_Float16*)(which ? YR : YL);
        float bv = (which ? br : bl)[lc];
        #pragma unroll
        for (int rt = 0; rt < 2; ++rt) {
            int rr = row0 + rbase + rt * 16 + quad * 4;
            #pragma unroll
            for (int g = 0; g < 4; ++g) {
                int r = rr + g;
                if (r < nrows) {
                    long idx;
                    if (HPL && which == 0)
                        idx = (long)(lc >> 6) * ((long)nrows * 64) + (long)r * 64 + (lc & 63);
                    else
                        idx = (long)r * CPW + lc;
                    Y[idx] = (_Float16)(acc[rt][ct][g] + bv);
                }
            }
        }
    }
}

// ---------------- CSR build ----------------
// Pass A: rank of each edge within its dst bucket (atomic+ret, coalesced store).
__global__ __launch_bounds__(256) void rank_k(
    const int* __restrict__ ei, int* __restrict__ cnt, int* __restrict__ rnk,
    int E0, int N)
{
    int e = blockIdx.x * 1024 + threadIdx.x;
    int ET = E0 + N;
    #pragma unroll
    for (int u = 0; u < 4; ++u, e += 256) {
        if (e < ET) {
            int dst = (e < E0) ? ei[E0 + e] : (e - E0);
            rnk[e] = atomicAdd(&cnt[dst], 1);
        }
    }
}

__global__ __launch_bounds__(256) void scan1_k(
    const int* __restrict__ cnt, int* __restrict__ loc, int* __restrict__ bsum, int n)
{
    __shared__ int wsum[4];
    int t = threadIdx.x;
    int i0 = blockIdx.x * 1024 + t * 4;
    int4 v;
    v.x = (i0 + 0 < n) ? cnt[i0 + 0] : 0;
    v.y = (i0 + 1 < n) ? cnt[i0 + 1] : 0;
    v.z = (i0 + 2 < n) ? cnt[i0 + 2] : 0;
    v.w = (i0 + 3 < n) ? cnt[i0 + 3] : 0;
    int tsum = v.x + v.y + v.z + v.w;
    int incl = tsum;
    #pragma unroll
    for (int s = 1; s < 64; s <<= 1) {
        int u = __shfl_up(incl, s, 64);
        if ((t & 63) >= s) incl += u;
    }
    int wid = t >> 6;
    if ((t & 63) == 63) wsum[wid] = incl;
    __syncthreads();
    int woff = 0;
    #pragma unroll
    for (int w = 0; w < 4; ++w) if (w < wid) woff += wsum[w];
    int ex = woff + incl - tsum;
    if (i0 + 0 < n) loc[i0 + 0] = ex;
    if (i0 + 1 < n) loc[i0 + 1] = ex + v.x;
    if (i0 + 2 < n) loc[i0 + 2] = ex + v.x + v.y;
    if (i0 + 3 < n) loc[i0 + 3] = ex + v.x + v.y + v.z;
    if (t == 255) bsum[blockIdx.x] = woff + incl;
}

__global__ void scan2_k(const int* __restrict__ bsum, int* __restrict__ bcarry,
                        int M, int* __restrict__ total_out)
{
    int lane = threadIdx.x;
    int carry = 0;
    for (int base = 0; base < M; base += 64) {
        int i = base + lane;
        int v = (i < M) ? bsum[i] : 0;
        int incl = v;
        #pragma unroll
        for (int s = 1; s < 64; s <<= 1) {
            int u = __shfl_up(incl, s, 64);
            if (lane >= s) incl += u;
        }
        if (i < M) bcarry[i] = carry + incl - v;
        carry += __shfl(incl, 63, 64);
    }
    if (lane == 0) *total_out = carry;
}

__global__ __launch_bounds__(256) void scan3_k(
    int* __restrict__ off, const int* __restrict__ bcarry, int n)
{
    int i = blockIdx.x * 256 + threadIdx.x;
    if (i >= n) return;
    off[i] += bcarry[i >> 10];
}

// Pass C: scatter src into its CSR slot (no atomics, full MLP).
__global__ __launch_bounds__(256) void scatter_k(
    const int* __restrict__ ei, const int* __restrict__ off_,
    const int* __restrict__ rnk, int* __restrict__ srcs, int E0, int N)
{
    int e = blockIdx.x * 1024 + threadIdx.x;
    int ET = E0 + N;
    #pragma unroll
    for (int u = 0; u < 4; ++u, e += 256) {
        if (e < ET) {
            int src = (e < E0) ? ei[e]      : (e - E0);
            int dst = (e < E0) ? ei[E0 + e] : (e - E0);
            srcs[off_[dst] + rnk[e]] = src;
        }
    }
}

// ---------------- fused score + softmax + aggregation, per dst node ----------------
// Layer 1, head-pair split: pass p handles heads {2p, 2p+1} = feats [64p, 64p+64).
// XLp layout [2][N][64] (head-pair-major) so the per-pass gather working set is
// 12.8 MB (vs 25.6) -> higher L2 hit rate on the random src gather.
// One node per 8-lane group (32 nodes/block); lane owns 8 feats (uint4 = 16 B);
// head = quad, score reduce = 2 DPP adds within the quad. Depth-2 row prefetch.
template<bool RELU>
__global__ __launch_bounds__(256) void fused128hp_k(
    const __half* __restrict__ XLp, const __half* __restrict__ XR,
    const float* __restrict__ ATT, const int* __restrict__ srcs,
    const int* __restrict__ off, const float* __restrict__ bias,
    __half* __restrict__ OUT, int N, int p)
{
    const int t   = threadIdx.x;
    const int d   = blockIdx.x * 32 + (t >> 3);   // node for this 8-lane group
    const int sub = t & 7;                        // feats 64p + 8*sub .. +8
    const bool nv = d < N;

    int a = 0, b = 0;
    if (nv) { a = off[d]; b = off[d + 1]; }

    __half2 xr[4] = { u2h2(0), u2h2(0), u2h2(0), u2h2(0) };
    if (nv) {
        uint4 ur = *(const uint4*)(XR + (long)d * 128 + p * 64 + sub * 8);
        xr[0] = u2h2(ur.x); xr[1] = u2h2(ur.y); xr[2] = u2h2(ur.z); xr[3] = u2h2(ur.w);
    }
    float4 at0f = ((const float4*)ATT)[p * 16 + sub * 2];
    float4 at1f = ((const float4*)ATT)[p * 16 + sub * 2 + 1];
    __half2 at[4] = { __floats2half2_rn(at0f.x, at0f.y), __floats2half2_rn(at0f.z, at0f.w),
                      __floats2half2_rn(at1f.x, at1f.y), __floats2half2_rn(at1f.z, at1f.w) };
    const __half2 neg2 = __float2half2_rn(NEG);

    float l = 0.f;
    float accv[8] = {0.f,0.f,0.f,0.f,0.f,0.f,0.f,0.f};

    const uint4* XL4 = (const uint4*)(XLp + (size_t)p * N * 64);

    if (b > a) {   // degree >= 1 always for valid nodes (self-loops)
        const int bm1 = b - 1;
        int sA = srcs[a];
        uint4 r0 = XL4[(long)sA * 8 + sub];
        int i1 = (a + 1 < bm1) ? a + 1 : bm1;
        int sB = srcs[i1];
        uint4 r1 = XL4[(long)sB * 8 + sub];
        int i2 = (a + 2 < bm1) ? a + 2 : bm1;
        int s2 = srcs[i2];

        for (int e = a; e < b; ++e) {
            uint4 r2 = XL4[(long)s2 * 8 + sub];   // row for e+2
            int i3 = (e + 3 < bm1) ? e + 3 : bm1;
            int s3 = srcs[i3];                    // srcs for e+3

            __half2 x0 = u2h2(r0.x), x1 = u2h2(r0.y), x2 = u2h2(r0.z), x3 = u2h2(r0.w);
            __half2 s0h = __hadd2(x0, xr[0]);
            __half2 s1h = __hadd2(x1, xr[1]);
            __half2 s2h = __hadd2(x2, xr[2]);
            __half2 s3h = __hadd2(x3, xr[3]);
            __half2 q0 = hmax2(s0h, __hmul2(s0h, neg2));
            __half2 q1 = hmax2(s1h, __hmul2(s1h, neg2));
            __half2 q2 = hmax2(s2h, __hmul2(s2h, neg2));
            __half2 q3 = hmax2(s3h, __hmul2(s3h, neg2));
            float p0 = fdot2h(q0, at[0], 0.f);
            p0 = fdot2h(q1, at[1], p0);
            p0 = fdot2h(q2, at[2], p0);
            p0 = fdot2h(q3, at[3], p0);
            // reduce over the 4-lane head quad
            p0 = dppadd<0xB1>(p0);   // + lane^1
            p0 = dppadd<0x4E>(p0);   // + lane^2
            float ex = __expf(p0);
            l += ex;
            float2 f0 = __half22float2(x0), f1 = __half22float2(x1);
            float2 f2 = __half22float2(x2), f3 = __half22float2(x3);
            accv[0] += ex * f0.x; accv[1] += ex * f0.y;
            accv[2] += ex * f1.x; accv[3] += ex * f1.y;
            accv[4] += ex * f2.x; accv[5] += ex * f2.y;
            accv[6] += ex * f3.x; accv[7] += ex * f3.y;

            r0 = r1; r1 = r2; s2 = s3;
        }
    }

    if (nv) {
        float inv = 1.f / l;
        float4 b0 = ((const float4*)bias)[p * 16 + sub * 2];
        float4 b1 = ((const float4*)bias)[p * 16 + sub * 2 + 1];
        float o[8] = { accv[0]*inv + b0.x, accv[1]*inv + b0.y,
                       accv[2]*inv + b0.z, accv[3]*inv + b0.w,
                       accv[4]*inv + b1.x, accv[5]*inv + b1.y,
                       accv[6]*inv + b1.z, accv[7]*inv + b1.w };
        if constexpr (RELU) {
            #pragma unroll
            for (int j = 0; j < 8; ++j) o[j] = fmaxf(o[j], 0.f);
        }
        uint4 uo;
        uo.x = __builtin_bit_cast(unsigned int, __floats2half2_rn(o[0], o[1]));
        uo.y = __builtin_bit_cast(unsigned int, __floats2half2_rn(o[2], o[3]));
        uo.z = __builtin_bit_cast(unsigned int, __floats2half2_rn(o[4], o[5]));
        uo.w = __builtin_bit_cast(unsigned int, __floats2half2_rn(o[6], o[7]));
        *(uint4*)(OUT + (long)d * 128 + p * 64 + sub * 8) = uo;
    }
}

// Layer 2: H=1, C=64. One node per 8-lane GROUP (32 nodes/block, 8/wave);
// each lane owns 8 consecutive feats. Score reduce = 3 DPP adds over 8 lanes.
// Depth-2 prefetch.
template<bool RELU>
__global__ __launch_bounds__(256) void fused64_k(
    const __half* __restrict__ XL, const __half* __restrict__ XR,
    const float* __restrict__ ATT, const int* __restrict__ srcs,
    const int* __restrict__ off, const float* __restrict__ bias,
    float* __restrict__ OUT, int N)
{
    const int t   = threadIdx.x;
    const int d   = blockIdx.x * 32 + (t >> 3);   // node for this 8-lane group
    const int sub = t & 7;                        // feats 8*sub..8*sub+7
    const bool nv = d < N;

    int a = 0, b = 0;
    if (nv) { a = off[d]; b = off[d + 1]; }

    __half2 xr[4] = { u2h2(0), u2h2(0), u2h2(0), u2h2(0) };
    if (nv) {
        uint4 ur = *(const uint4*)(XR + (long)d * 64 + sub * 8);
        xr[0] = u2h2(ur.x); xr[1] = u2h2(ur.y); xr[2] = u2h2(ur.z); xr[3] = u2h2(ur.w);
    }
    float4 at0f = ((const float4*)ATT)[sub * 2];
    float4 at1f = ((const float4*)ATT)[sub * 2 + 1];
    __half2 at[4] = { __floats2half2_rn(at0f.x, at0f.y), __floats2half2_rn(at0f.z, at0f.w),
                      __floats2half2_rn(at1f.x, at1f.y), __floats2half2_rn(at1f.z, at1f.w) };
    const __half2 neg2 = __float2half2_rn(NEG);

    float l = 0.f;
    float accv[8] = {0.f,0.f,0.f,0.f,0.f,0.f,0.f,0.f};

    const uint4* XL4 = (const uint4*)XL;

    if (b > a) {
        const int bm1 = b - 1;
        int sA = srcs[a];
        uint4 r0 = XL4[(long)sA * 8 + sub];
        int i1 = (a + 1 < bm1) ? a + 1 : bm1;
        int sB = srcs[i1];
        uint4 r1 = XL4[(long)sB * 8 + sub];
        int i2 = (a + 2 < bm1) ? a + 2 : bm1;
        int s2 = srcs[i2];

        for (int e = a; e < b; ++e) {
            uint4 r2 = XL4[(long)s2 * 8 + sub];
            int i3 = (e + 3 < bm1) ? e + 3 : bm1;
            int s3 = srcs[i3];

            __half2 x0 = u2h2(r0.x), x1 = u2h2(r0.y), x2 = u2h2(r0.z), x3 = u2h2(r0.w);
            __half2 s0h = __hadd2(x0, xr[0]);
            __half2 s1h = __hadd2(x1, xr[1]);
            __half2 s2h = __hadd2(x2, xr[2]);
            __half2 s3h = __hadd2(x3, xr[3]);
            __half2 q0 = hmax2(s0h, __hmul2(s0h, neg2));
            __half2 q1 = hmax2(s1h, __hmul2(s1h, neg2));
            __half2 q2 = hmax2(s2h, __hmul2(s2h, neg2));
            __half2 q3 = hmax2(s3h, __hmul2(s3h, neg2));
            float p0 = fdot2h(q0, at[0], 0.f);
            p0 = fdot2h(q1, at[1], p0);
            p0 = fdot2h(q2, at[2], p0);
            p0 = fdot2h(q3, at[3], p0);
            // reduce over the 8-lane group
            p0 = dppadd<0xB1>(p0);    // + lane^1
            p0 = dppadd<0x4E>(p0);    // + lane^2
            p0 = dppadd<0x141>(p0);   // row_half_mirror == xor4 at this stage
            float ex = __expf(p0);
            l += ex;
            float2 f0 = __half22float2(x0), f1 = __half22float2(x1);
            float2 f2 = __half22float2(x2), f3 = __half22float2(x3);
            accv[0] += ex * f0.x; accv[1] += ex * f0.y;
            accv[2] += ex * f1.x; accv[3] += ex * f1.y;
            accv[4] += ex * f2.x; accv[5] += ex * f2.y;
            accv[6] += ex * f3.x; accv[7] += ex * f3.y;

            r0 = r1; r1 = r2; s2 = s3;
        }
    }

    if (nv) {
        float inv = 1.f / l;
        float4 b0 = ((const float4*)bias)[sub * 2];
        float4 b1 = ((const float4*)bias)[sub * 2 + 1];
        float4 o0 = make_float4(accv[0]*inv + b0.x, accv[1]*inv + b0.y,
                                accv[2]*inv + b0.z, accv[3]*inv + b0.w);
        float4 o1 = make_float4(accv[4]*inv + b1.x, accv[5]*inv + b1.y,
                                accv[6]*inv + b1.z, accv[7]*inv + b1.w);
        if constexpr (RELU) {
            o0.x = fmaxf(o0.x, 0.f); o0.y = fmaxf(o0.y, 0.f);
            o0.z = fmaxf(o0.z, 0.f); o0.w = fmaxf(o0.w, 0.f);
            o1.x = fmaxf(o1.x, 0.f); o1.y = fmaxf(o1.y, 0.f);
            o1.z = fmaxf(o1.z, 0.f); o1.w = fmaxf(o1.w, 0.f);
        }
        *(float4*)(OUT + (long)d * 64 + sub * 8)     = o0;
        *(float4*)(OUT + (long)d * 64 + sub * 8 + 4) = o1;
    }
}

extern "C" void kernel_launch(void* const* d_in, const int* in_sizes, int n_in,
                              void* d_out, int out_size, void* d_ws, size_t ws_size,
                              hipStream_t stream)
{
    const float* x     = (const float*)d_in[0];
    const int*   ei    = (const int*)  d_in[1];
    const float* Wl1   = (const float*)d_in[2];
    const float* bl1   = (const float*)d_in[3];
    const float* Wr1   = (const float*)d_in[4];
    const float* br1   = (const float*)d_in[5];
    const float* att1  = (const float*)d_in[6];
    const float* bias1 = (const float*)d_in[7];
    const float* Wl2   = (const float*)d_in[8];
    const float* bl2   = (const float*)d_in[9];
    const float* Wr2   = (const float*)d_in[10];
    const float* br2   = (const float*)d_in[11];
    const float* att2  = (const float*)d_in[12];
    const float* bias2 = (const float*)d_in[13];

    const int  N  = in_sizes[0] / 128;
    const int  E0 = in_sizes[1] / 2;
    const long ET = (long)E0 + N;
    const int  NB = (N + 1023) / 1024;

    char* w = (char*)d_ws;
    __half* XLh = (__half*)w;                         // N*128 halfs ([2][N][64] for layer 1)
    __half* XRh = XLh + (size_t)N * 128;              // N*128 halfs
    __half* Cch = XRh + (size_t)N * 128;              // N*128 halfs
    int*    off = (int*)(Cch + (size_t)N * 128);      // N+1
    int*    cnt = off + (N + 1);                      // N
    int*    srcs= cnt + N;                            // ET
    int*    rnk = srcs + ET;                          // ET
    int*    bsum= rnk + ET;                           // NB
    int*    bcar= bsum + NB;                          // NB
    float*  out = (float*)d_out;

    dim3 b256(256);
    const int e4blk = (int)((ET + 1023) / 1024);
    const int gx    = (N + 127) / 128;
    const int ng32  = (N + 31) / 32;

    // ---- CSR build ----
    (void)hipMemsetAsync(cnt, 0, (size_t)N * 4, stream);
    rank_k<<<e4blk, b256, 0, stream>>>(ei, cnt, rnk, E0, N);
    scan1_k<<<NB, b256, 0, stream>>>(cnt, off, bsum, N);
    scan2_k<<<1, 64, 0, stream>>>(bsum, bcar, NB, off + N);
    scan3_k<<<(N + 255) / 256, b256, 0, stream>>>(off, bcar, N);
    scatter_k<<<e4blk, b256, 0, stream>>>(ei, off, rnk, srcs, E0, N);

    // ---- layer 1 ----
    mfma_gemm_k<128, false, true><<<dim3(gx, 2), b256, 0, stream>>>(
        x, nullptr, Wl1, bl1, Wr1, br1, XLh, XRh, N);
    // two sequential head-pair passes (working sets don't merge)
    fused128hp_k<true><<<ng32, b256, 0, stream>>>(XLh, XRh, att1, srcs, off, bias1, Cch, N, 0);
    fused128hp_k<true><<<ng32, b256, 0, stream>>>(XLh, XRh, att1, srcs, off, bias1, Cch, N, 1);

    // ---- layer 2 ----
    mfma_gemm_k<64, true, false><<<dim3(gx, 1), b256, 0, stream>>>(
        nullptr, Cch, Wl2, bl2, Wr2, br2, XLh, XRh, N);
    fused64_k<false><<<ng32, b256, 0, stream>>>(XLh, XRh, att2, srcs, off, bias2, out, N);
}

// Round 6
// 406.827 us; speedup vs baseline: 1.1461x; 1.1461x over previous
//
#include <hip/hip_runtime.h>
#include <hip/hip_fp16.h>

#define NEG 0.2f

typedef _Float16 f16x8 __attribute__((ext_vector_type(8)));
typedef _Float16 f16x2 __attribute__((ext_vector_type(2)));
typedef float    f32x4 __attribute__((ext_vector_type(4)));

__device__ __forceinline__ float fdot2h(__half2 a, __half2 b, float c) {
    return __builtin_amdgcn_fdot2(__builtin_bit_cast(f16x2, a),
                                  __builtin_bit_cast(f16x2, b), c, false);
}

__device__ __forceinline__ __half2 u2h2(unsigned int u) {
    return __builtin_bit_cast(__half2, u);
}

// packed half2 max via v_pk_max_f16 (ROCm header lacks __hmax2 on this toolchain)
__device__ __forceinline__ __half2 hmax2(__half2 a, __half2 b) {
    unsigned int ua = __builtin_bit_cast(unsigned int, a);
    unsigned int ub = __builtin_bit_cast(unsigned int, b);
    unsigned int ud;
    asm("v_pk_max_f16 %0, %1, %2" : "=v"(ud) : "v"(ua), "v"(ub));
    return __builtin_bit_cast(__half2, ud);
}

// ---- DPP cross-lane add via compiler intrinsic (hazards handled by compiler).
// CTRL: 0xB1 = quad_perm[1,0,3,2] (lane^1), 0x4E = quad_perm[2,3,0,1] (lane^2),
//       0x141 = row_half_mirror (==xor4 after the xor1,xor2 stages).
template<int CTRL>
__device__ __forceinline__ float dppadd(float x) {
    int xi = __builtin_bit_cast(int, x);
    int yi = __builtin_amdgcn_update_dpp(0, xi, CTRL, 0xf, 0xf, true);
    return x + __builtin_bit_cast(float, yi);
}

// ---------------- MFMA GEMM: Y = half(X[N,128] @ [Wl|Wr] + bias) ----------------
// HPL: write YL head-pair-major as [2][N][64] (for the head-split fused layer-1).
template<int CPW, bool IN_F16, bool HPL>
__global__ __launch_bounds__(256) void mfma_gemm_k(
    const float* __restrict__ Xf, const __half* __restrict__ Xh,
    const float* __restrict__ Wl, const float* __restrict__ bl,
    const float* __restrict__ Wr, const float* __restrict__ br,
    __half* __restrict__ YL, __half* __restrict__ YR, int nrows)
{
    __shared__ _Float16 Xs[128 * 136];
    __shared__ _Float16 Ws[128 * 136];

    const int t    = threadIdx.x;
    const int row0 = blockIdx.x * 128;
    const int c0   = blockIdx.y * 128;

    if constexpr (IN_F16) {
        for (int i = t; i < 128 * 16; i += 256) {
            int r = i >> 4, c = i & 15;
            int gr = row0 + r;
            uint4 v = make_uint4(0u, 0u, 0u, 0u);
            if (gr < nrows) v = ((const uint4*)Xh)[(long)gr * 16 + c];
            *(uint4*)&Xs[r * 136 + c * 8] = v;
        }
    } else {
        for (int i = t; i < 128 * 16; i += 256) {
            int r = i >> 4, c = i & 15;
            int gr = row0 + r;
            float4 a = make_float4(0.f,0.f,0.f,0.f), b4 = make_float4(0.f,0.f,0.f,0.f);
            if (gr < nrows) {
                a  = ((const float4*)Xf)[(long)gr * 32 + c * 2];
                b4 = ((const float4*)Xf)[(long)gr * 32 + c * 2 + 1];
            }
            _Float16 h[8] = {(_Float16)a.x,(_Float16)a.y,(_Float16)a.z,(_Float16)a.w,
                             (_Float16)b4.x,(_Float16)b4.y,(_Float16)b4.z,(_Float16)b4.w};
            *(f16x8*)&Xs[r * 136 + c * 8] = *(f16x8*)h;
        }
    }

    for (int i = t; i < 128 * 128; i += 256) {
        int k = i >> 7, n = i & 127;
        int gc = c0 + n;
        const float* Wp = (gc >= CPW) ? Wr : Wl;
        int lc = gc & (CPW - 1);
        Ws[n * 136 + k] = (_Float16)Wp[(long)k * CPW + lc];
    }
    __syncthreads();

    const int lane  = t & 63;
    const int wv    = t >> 6;
    const int m     = lane & 15;
    const int quad  = lane >> 4;
    const int rbase = wv * 32;

    f16x8 Af[2][4];
    #pragma unroll
    for (int rt = 0; rt < 2; ++rt)
        #pragma unroll
        for (int ks = 0; ks < 4; ++ks)
            Af[rt][ks] = *(const f16x8*)&Xs[(rbase + rt * 16 + m) * 136 + ks * 32 + quad * 8];

    f32x4 acc[2][8];
    #pragma unroll
    for (int rt = 0; rt < 2; ++rt)
        #pragma unroll
        for (int ct = 0; ct < 8; ++ct)
            acc[rt][ct] = (f32x4){0.f, 0.f, 0.f, 0.f};

    #pragma unroll
    for (int ct = 0; ct < 8; ++ct) {
        #pragma unroll
        for (int ks = 0; ks < 4; ++ks) {
            f16x8 Bf = *(const f16x8*)&Ws[(ct * 16 + m) * 136 + ks * 32 + quad * 8];
            acc[0][ct] = __builtin_amdgcn_mfma_f32_16x16x32_f16(Af[0][ks], Bf, acc[0][ct], 0, 0, 0);
            acc[1][ct] = __builtin_amdgcn_mfma_f32_16x16x32_f16(Af[1][ks], Bf, acc[1][ct], 0, 0, 0);
        }
    }

    #pragma unroll
    for (int ct = 0; ct < 8; ++ct) {
        int gc = c0 + ct * 16 + m;
        int which = gc / CPW;
        int lc = gc % CPW;
        _Float16* Y = (_Float16*)(which ? YR : YL);
        float bv = (which ? br : bl)[lc];
        #pragma unroll
        for (int rt = 0; rt < 2; ++rt) {
            int rr = row0 + rbase + rt * 16 + quad * 4;
            #pragma unroll
            for (int g = 0; g < 4; ++g) {
                int r = rr + g;
                if (r < nrows) {
                    long idx;
                    if (HPL && which == 0)
                        idx = (long)(lc >> 6) * ((long)nrows * 64) + (long)r * 64 + (lc & 63);
                    else
                        idx = (long)r * CPW + lc;
                    Y[idx] = (_Float16)(acc[rt][ct][g] + bv);
                }
            }
        }
    }
}

// ---------------- CSR build via MSD counting-sort (NO global atomics) ----------
// Coarse bucket = dst>>9 (196 buckets). Within a bucket, bin = dst&511 == exact
// dst, so no stability is required anywhere (softmax order-invariant).

// Pass 1a: per-block 256-bin histogram of dst>>9. gh layout [bin][blk].
__global__ __launch_bounds__(256) void h1_k(
    const int* __restrict__ ei, int* __restrict__ gh, int E0, int ET, int NBK)
{
    __shared__ int h[256];
    const int t = threadIdx.x, blk = blockIdx.x;
    h[t] = 0;
    __syncthreads();
    int e = blk * 4096 + t;
    #pragma unroll
    for (int u = 0; u < 16; ++u, e += 256) {
        if (e < ET) {
            int dst = (e < E0) ? ei[E0 + e] : (e - E0);
            atomicAdd(&h[dst >> 9], 1);
        }
    }
    __syncthreads();
    gh[t * NBK + blk] = h[t];
}

// scan1/2/3: generic exclusive scan (reused for gh, in-place).
__global__ __launch_bounds__(256) void scan1_k(
    const int* __restrict__ cnt, int* __restrict__ loc, int* __restrict__ bsum, int n)
{
    __shared__ int wsum[4];
    int t = threadIdx.x;
    int i0 = blockIdx.x * 1024 + t * 4;
    int4 v;
    v.x = (i0 + 0 < n) ? cnt[i0 + 0] : 0;
    v.y = (i0 + 1 < n) ? cnt[i0 + 1] : 0;
    v.z = (i0 + 2 < n) ? cnt[i0 + 2] : 0;
    v.w = (i0 + 3 < n) ? cnt[i0 + 3] : 0;
    int tsum = v.x + v.y + v.z + v.w;
    int incl = tsum;
    #pragma unroll
    for (int s = 1; s < 64; s <<= 1) {
        int u = __shfl_up(incl, s, 64);
        if ((t & 63) >= s) incl += u;
    }
    int wid = t >> 6;
    if ((t & 63) == 63) wsum[wid] = incl;
    __syncthreads();
    int woff = 0;
    #pragma unroll
    for (int w = 0; w < 4; ++w) if (w < wid) woff += wsum[w];
    int ex = woff + incl - tsum;
    if (i0 + 0 < n) loc[i0 + 0] = ex;
    if (i0 + 1 < n) loc[i0 + 1] = ex + v.x;
    if (i0 + 2 < n) loc[i0 + 2] = ex + v.x + v.y;
    if (i0 + 3 < n) loc[i0 + 3] = ex + v.x + v.y + v.z;
    if (t == 255) bsum[blockIdx.x] = woff + incl;
}

__global__ void scan2_k(const int* __restrict__ bsum, int* __restrict__ bcarry,
                        int M, int* __restrict__ total_out)
{
    int lane = threadIdx.x;
    int carry = 0;
    for (int base = 0; base < M; base += 64) {
        int i = base + lane;
        int v = (i < M) ? bsum[i] : 0;
        int incl = v;
        #pragma unroll
        for (int s = 1; s < 64; s <<= 1) {
            int u = __shfl_up(incl, s, 64);
            if (lane >= s) incl += u;
        }
        if (i < M) bcarry[i] = carry + incl - v;
        carry += __shfl(incl, 63, 64);
    }
    if (lane == 0) *total_out = carry;
}

__global__ __launch_bounds__(256) void scan3_k(
    int* __restrict__ off, const int* __restrict__ bcarry, int n)
{
    int i = blockIdx.x * 256 + threadIdx.x;
    if (i >= n) return;
    off[i] += bcarry[i >> 10];
}

// Pass 1b: partition edges into coarse buckets. LDS running offsets seeded from
// the scanned gh; position via LDS atomic (within-bucket order arbitrary = OK).
__global__ __launch_bounds__(256) void sc1_k(
    const int* __restrict__ ei, const int* __restrict__ gh,
    uint2* __restrict__ rec, int E0, int ET, int NBK)
{
    __shared__ int lofs[256];
    const int t = threadIdx.x, blk = blockIdx.x;
    lofs[t] = gh[t * NBK + blk];
    __syncthreads();
    int e = blk * 4096 + t;
    #pragma unroll
    for (int u = 0; u < 16; ++u, e += 256) {
        if (e < ET) {
            int src = (e < E0) ? ei[e]      : (e - E0);
            int dst = (e < E0) ? ei[E0 + e] : (e - E0);
            int p = atomicAdd(&lofs[dst >> 9], 1);
            rec[p] = make_uint2((unsigned)src, (unsigned)dst);
        }
    }
}

// Pass 2: one block per coarse bucket. 512-bin LDS histogram of dst&511
// (== exact dst), LDS scan -> off[] written directly (every node has a
// self-loop so every valid bin is non-empty), then place srcs.
__global__ __launch_bounds__(256) void p2_k(
    const uint2* __restrict__ rec, const int* __restrict__ gh,
    int* __restrict__ srcs, int* __restrict__ off, int N, int NBK)
{
    __shared__ int hist[512];
    __shared__ int sc[2][512];
    __shared__ int curo[512];
    const int t = threadIdx.x;
    const int b = blockIdx.x;
    const int base = gh[b * NBK];
    const int end  = gh[(b + 1) * NBK];   // bins >195 empty -> works for last bucket
    hist[t] = 0; hist[t + 256] = 0;
    __syncthreads();
    for (int i = base + t; i < end; i += 256) {
        uint2 r = rec[i];
        atomicAdd(&hist[r.y & 511], 1);
    }
    __syncthreads();
    sc[0][t] = hist[t]; sc[0][t + 256] = hist[t + 256];
    __syncthreads();
    int pp = 0;
    for (int s = 1; s < 512; s <<= 1, pp ^= 1) {
        int j0 = t, j1 = t + 256;
        sc[pp ^ 1][j0] = sc[pp][j0] + ((j0 >= s) ? sc[pp][j0 - s] : 0);
        sc[pp ^ 1][j1] = sc[pp][j1] + ((j1 >= s) ? sc[pp][j1 - s] : 0);
        __syncthreads();
    }
    {
        int j0 = t, j1 = t + 256;
        int e0 = base + sc[pp][j0] - hist[j0];
        int e1 = base + sc[pp][j1] - hist[j1];
        curo[j0] = e0;
        curo[j1] = e1;
        int d0 = b * 512 + j0, d1 = b * 512 + j1;
        if (d0 < N) off[d0] = e0;
        if (d1 < N) off[d1] = e1;
    }
    __syncthreads();
    for (int i = base + t; i < end; i += 256) {
        uint2 r = rec[i];
        int pos = atomicAdd(&curo[r.y & 511], 1);
        srcs[pos] = (int)r.x;
    }
}

// ---------------- fused score + softmax + aggregation, per dst node ----------------
// Layer 1, head-pair split: pass p handles heads {2p, 2p+1} = feats [64p, 64p+64).
template<bool RELU>
__global__ __launch_bounds__(256) void fused128hp_k(
    const __half* __restrict__ XLp, const __half* __restrict__ XR,
    const float* __restrict__ ATT, const int* __restrict__ srcs,
    const int* __restrict__ off, const float* __restrict__ bias,
    __half* __restrict__ OUT, int N, int p)
{
    const int t   = threadIdx.x;
    const int d   = blockIdx.x * 32 + (t >> 3);   // node for this 8-lane group
    const int sub = t & 7;                        // feats 64p + 8*sub .. +8
    const bool nv = d < N;

    int a = 0, b = 0;
    if (nv) { a = off[d]; b = off[d + 1]; }

    __half2 xr[4] = { u2h2(0), u2h2(0), u2h2(0), u2h2(0) };
    if (nv) {
        uint4 ur = *(const uint4*)(XR + (long)d * 128 + p * 64 + sub * 8);
        xr[0] = u2h2(ur.x); xr[1] = u2h2(ur.y); xr[2] = u2h2(ur.z); xr[3] = u2h2(ur.w);
    }
    float4 at0f = ((const float4*)ATT)[p * 16 + sub * 2];
    float4 at1f = ((const float4*)ATT)[p * 16 + sub * 2 + 1];
    __half2 at[4] = { __floats2half2_rn(at0f.x, at0f.y), __floats2half2_rn(at0f.z, at0f.w),
                      __floats2half2_rn(at1f.x, at1f.y), __floats2half2_rn(at1f.z, at1f.w) };
    const __half2 neg2 = __float2half2_rn(NEG);

    float l = 0.f;
    float accv[8] = {0.f,0.f,0.f,0.f,0.f,0.f,0.f,0.f};

    const uint4* XL4 = (const uint4*)(XLp + (size_t)p * N * 64);

    if (b > a) {   // degree >= 1 always for valid nodes (self-loops)
        const int bm1 = b - 1;
        int sA = srcs[a];
        uint4 r0 = XL4[(long)sA * 8 + sub];
        int i1 = (a + 1 < bm1) ? a + 1 : bm1;
        int sB = srcs[i1];
        uint4 r1 = XL4[(long)sB * 8 + sub];
        int i2 = (a + 2 < bm1) ? a + 2 : bm1;
        int s2 = srcs[i2];

        for (int e = a; e < b; ++e) {
            uint4 r2 = XL4[(long)s2 * 8 + sub];   // row for e+2
            int i3 = (e + 3 < bm1) ? e + 3 : bm1;
            int s3 = srcs[i3];                    // srcs for e+3

            __half2 x0 = u2h2(r0.x), x1 = u2h2(r0.y), x2 = u2h2(r0.z), x3 = u2h2(r0.w);
            __half2 s0h = __hadd2(x0, xr[0]);
            __half2 s1h = __hadd2(x1, xr[1]);
            __half2 s2h = __hadd2(x2, xr[2]);
            __half2 s3h = __hadd2(x3, xr[3]);
            __half2 q0 = hmax2(s0h, __hmul2(s0h, neg2));
            __half2 q1 = hmax2(s1h, __hmul2(s1h, neg2));
            __half2 q2 = hmax2(s2h, __hmul2(s2h, neg2));
            __half2 q3 = hmax2(s3h, __hmul2(s3h, neg2));
            float p0 = fdot2h(q0, at[0], 0.f);
            p0 = fdot2h(q1, at[1], p0);
            p0 = fdot2h(q2, at[2], p0);
            p0 = fdot2h(q3, at[3], p0);
            // reduce over the 4-lane head quad
            p0 = dppadd<0xB1>(p0);   // + lane^1
            p0 = dppadd<0x4E>(p0);   // + lane^2
            float ex = __expf(p0);
            l += ex;
            float2 f0 = __half22float2(x0), f1 = __half22float2(x1);
            float2 f2 = __half22float2(x2), f3 = __half22float2(x3);
            accv[0] += ex * f0.x; accv[1] += ex * f0.y;
            accv[2] += ex * f1.x; accv[3] += ex * f1.y;
            accv[4] += ex * f2.x; accv[5] += ex * f2.y;
            accv[6] += ex * f3.x; accv[7] += ex * f3.y;

            r0 = r1; r1 = r2; s2 = s3;
        }
    }

    if (nv) {
        float inv = 1.f / l;
        float4 b0 = ((const float4*)bias)[p * 16 + sub * 2];
        float4 b1 = ((const float4*)bias)[p * 16 + sub * 2 + 1];
        float o[8] = { accv[0]*inv + b0.x, accv[1]*inv + b0.y,
                       accv[2]*inv + b0.z, accv[3]*inv + b0.w,
                       accv[4]*inv + b1.x, accv[5]*inv + b1.y,
                       accv[6]*inv + b1.z, accv[7]*inv + b1.w };
        if constexpr (RELU) {
            #pragma unroll
            for (int j = 0; j < 8; ++j) o[j] = fmaxf(o[j], 0.f);
        }
        uint4 uo;
        uo.x = __builtin_bit_cast(unsigned int, __floats2half2_rn(o[0], o[1]));
        uo.y = __builtin_bit_cast(unsigned int, __floats2half2_rn(o[2], o[3]));
        uo.z = __builtin_bit_cast(unsigned int, __floats2half2_rn(o[4], o[5]));
        uo.w = __builtin_bit_cast(unsigned int, __floats2half2_rn(o[6], o[7]));
        *(uint4*)(OUT + (long)d * 128 + p * 64 + sub * 8) = uo;
    }
}

// Layer 2: H=1, C=64. One node per 8-lane GROUP (32 nodes/block, 8/wave);
// each lane owns 8 consecutive feats. Score reduce = 3 DPP adds over 8 lanes.
template<bool RELU>
__global__ __launch_bounds__(256) void fused64_k(
    const __half* __restrict__ XL, const __half* __restrict__ XR,
    const float* __restrict__ ATT, const int* __restrict__ srcs,
    const int* __restrict__ off, const float* __restrict__ bias,
    float* __restrict__ OUT, int N)
{
    const int t   = threadIdx.x;
    const int d   = blockIdx.x * 32 + (t >> 3);   // node for this 8-lane group
    const int sub = t & 7;                        // feats 8*sub..8*sub+7
    const bool nv = d < N;

    int a = 0, b = 0;
    if (nv) { a = off[d]; b = off[d + 1]; }

    __half2 xr[4] = { u2h2(0), u2h2(0), u2h2(0), u2h2(0) };
    if (nv) {
        uint4 ur = *(const uint4*)(XR + (long)d * 64 + sub * 8);
        xr[0] = u2h2(ur.x); xr[1] = u2h2(ur.y); xr[2] = u2h2(ur.z); xr[3] = u2h2(ur.w);
    }
    float4 at0f = ((const float4*)ATT)[sub * 2];
    float4 at1f = ((const float4*)ATT)[sub * 2 + 1];
    __half2 at[4] = { __floats2half2_rn(at0f.x, at0f.y), __floats2half2_rn(at0f.z, at0f.w),
                      __floats2half2_rn(at1f.x, at1f.y), __floats2half2_rn(at1f.z, at1f.w) };
    const __half2 neg2 = __float2half2_rn(NEG);

    float l = 0.f;
    float accv[8] = {0.f,0.f,0.f,0.f,0.f,0.f,0.f,0.f};

    const uint4* XL4 = (const uint4*)XL;

    if (b > a) {
        const int bm1 = b - 1;
        int sA = srcs[a];
        uint4 r0 = XL4[(long)sA * 8 + sub];
        int i1 = (a + 1 < bm1) ? a + 1 : bm1;
        int sB = srcs[i1];
        uint4 r1 = XL4[(long)sB * 8 + sub];
        int i2 = (a + 2 < bm1) ? a + 2 : bm1;
        int s2 = srcs[i2];

        for (int e = a; e < b; ++e) {
            uint4 r2 = XL4[(long)s2 * 8 + sub];
            int i3 = (e + 3 < bm1) ? e + 3 : bm1;
            int s3 = srcs[i3];

            __half2 x0 = u2h2(r0.x), x1 = u2h2(r0.y), x2 = u2h2(r0.z), x3 = u2h2(r0.w);
            __half2 s0h = __hadd2(x0, xr[0]);
            __half2 s1h = __hadd2(x1, xr[1]);
            __half2 s2h = __hadd2(x2, xr[2]);
            __half2 s3h = __hadd2(x3, xr[3]);
            __half2 q0 = hmax2(s0h, __hmul2(s0h, neg2));
            __half2 q1 = hmax2(s1h, __hmul2(s1h, neg2));
            __half2 q2 = hmax2(s2h, __hmul2(s2h, neg2));
            __half2 q3 = hmax2(s3h, __hmul2(s3h, neg2));
            float p0 = fdot2h(q0, at[0], 0.f);
            p0 = fdot2h(q1, at[1], p0);
            p0 = fdot2h(q2, at[2], p0);
            p0 = fdot2h(q3, at[3], p0);
            // reduce over the 8-lane group
            p0 = dppadd<0xB1>(p0);    // + lane^1
            p0 = dppadd<0x4E>(p0);    // + lane^2
            p0 = dppadd<0x141>(p0);   // row_half_mirror == xor4 at this stage
            float ex = __expf(p0);
            l += ex;
            float2 f0 = __half22float2(x0), f1 = __half22float2(x1);
            float2 f2 = __half22float2(x2), f3 = __half22float2(x3);
            accv[0] += ex * f0.x; accv[1] += ex * f0.y;
            accv[2] += ex * f1.x; accv[3] += ex * f1.y;
            accv[4] += ex * f2.x; accv[5] += ex * f2.y;
            accv[6] += ex * f3.x; accv[7] += ex * f3.y;

            r0 = r1; r1 = r2; s2 = s3;
        }
    }

    if (nv) {
        float inv = 1.f / l;
        float4 b0 = ((const float4*)bias)[sub * 2];
        float4 b1 = ((const float4*)bias)[sub * 2 + 1];
        float4 o0 = make_float4(accv[0]*inv + b0.x, accv[1]*inv + b0.y,
                                accv[2]*inv + b0.z, accv[3]*inv + b0.w);
        float4 o1 = make_float4(accv[4]*inv + b1.x, accv[5]*inv + b1.y,
                                accv[6]*inv + b1.z, accv[7]*inv + b1.w);
        if constexpr (RELU) {
            o0.x = fmaxf(o0.x, 0.f); o0.y = fmaxf(o0.y, 0.f);
            o0.z = fmaxf(o0.z, 0.f); o0.w = fmaxf(o0.w, 0.f);
            o1.x = fmaxf(o1.x, 0.f); o1.y = fmaxf(o1.y, 0.f);
            o1.z = fmaxf(o1.z, 0.f); o1.w = fmaxf(o1.w, 0.f);
        }
        *(float4*)(OUT + (long)d * 64 + sub * 8)     = o0;
        *(float4*)(OUT + (long)d * 64 + sub * 8 + 4) = o1;
    }
}

extern "C" void kernel_launch(void* const* d_in, const int* in_sizes, int n_in,
                              void* d_out, int out_size, void* d_ws, size_t ws_size,
                              hipStream_t stream)
{
    const float* x     = (const float*)d_in[0];
    const int*   ei    = (const int*)  d_in[1];
    const float* Wl1   = (const float*)d_in[2];
    const float* bl1   = (const float*)d_in[3];
    const float* Wr1   = (const float*)d_in[4];
    const float* br1   = (const float*)d_in[5];
    const float* att1  = (const float*)d_in[6];
    const float* bias1 = (const float*)d_in[7];
    const float* Wl2   = (const float*)d_in[8];
    const float* bl2   = (const float*)d_in[9];
    const float* Wr2   = (const float*)d_in[10];
    const float* br2   = (const float*)d_in[11];
    const float* att2  = (const float*)d_in[12];
    const float* bias2 = (const float*)d_in[13];

    const int  N  = in_sizes[0] / 128;
    const int  E0 = in_sizes[1] / 2;
    const int  ET = E0 + N;

    char* w = (char*)d_ws;
    __half* XLh = (__half*)w;                         // N*128 halfs ([2][N][64] for layer 1)
    __half* XRh = XLh + (size_t)N * 128;              // N*128 halfs
    __half* Cch = XRh + (size_t)N * 128;              // N*128 halfs
    int*    off = (int*)(Cch + (size_t)N * 128);      // N+1
    int*    srcs= off + (N + 1);                      // ET
    int*    gh  = srcs + ET;                          // 256*NBK
    // rec aliases the XLh region: consumed by p2_k before the first GEMM runs.
    uint2*  rec = (uint2*)w;                          // ET * 8B  (<= N*128*2B)
    float*  out = (float*)d_out;

    dim3 b256(256);
    const int gx    = (N + 127) / 128;
    const int ng32  = (N + 31) / 32;

    const int NBK   = (ET + 4095) / 4096;
    const int n1    = 256 * NBK;
    const int NB1   = (n1 + 1023) / 1024;
    const int NBUCK = (N + 511) / 512;
    int* bsum = gh + n1;                              // NB1
    int* bcar = bsum + NB1;                           // NB1

    // ---- CSR build (counting sort, no global atomics) ----
    h1_k<<<NBK, b256, 0, stream>>>(ei, gh, E0, ET, NBK);
    scan1_k<<<NB1, b256, 0, stream>>>(gh, gh, bsum, n1);
    scan2_k<<<1, 64, 0, stream>>>(bsum, bcar, NB1, off + N);   // off[N] = ET
    scan3_k<<<(n1 + 255) / 256, b256, 0, stream>>>(gh, bcar, n1);
    sc1_k<<<NBK, b256, 0, stream>>>(ei, gh, rec, E0, ET, NBK);
    p2_k<<<NBUCK, b256, 0, stream>>>(rec, gh, srcs, off, N, NBK);

    // ---- layer 1 ----
    mfma_gemm_k<128, false, true><<<dim3(gx, 2), b256, 0, stream>>>(
        x, nullptr, Wl1, bl1, Wr1, br1, XLh, XRh, N);
    // two sequential head-pair passes (working sets don't merge)
    fused128hp_k<true><<<ng32, b256, 0, stream>>>(XLh, XRh, att1, srcs, off, bias1, Cch, N, 0);
    fused128hp_k<true><<<ng32, b256, 0, stream>>>(XLh, XRh, att1, srcs, off, bias1, Cch, N, 1);

    // ---- layer 2 ----
    mfma_gemm_k<64, true, false><<<dim3(gx, 1), b256, 0, stream>>>(
        nullptr, Cch, Wl2, bl2, Wr2, br2, XLh, XRh, N);
    fused64_k<false><<<ng32, b256, 0, stream>>>(XLh, XRh, att2, srcs, off, bias2, out, N);
}

// Round 7
// 367.948 us; speedup vs baseline: 1.2672x; 1.1057x over previous
//
#include <hip/hip_runtime.h>
#include <hip/hip_fp16.h>

#define NEG 0.2f

typedef _Float16 f16x8 __attribute__((ext_vector_type(8)));
typedef _Float16 f16x2 __attribute__((ext_vector_type(2)));
typedef float    f32x4 __attribute__((ext_vector_type(4)));

__device__ __forceinline__ float fdot2h(__half2 a, __half2 b, float c) {
    return __builtin_amdgcn_fdot2(__builtin_bit_cast(f16x2, a),
                                  __builtin_bit_cast(f16x2, b), c, false);
}

__device__ __forceinline__ __half2 u2h2(unsigned int u) {
    return __builtin_bit_cast(__half2, u);
}

// packed half2 max via v_pk_max_f16 (ROCm header lacks __hmax2 on this toolchain)
__device__ __forceinline__ __half2 hmax2(__half2 a, __half2 b) {
    unsigned int ua = __builtin_bit_cast(unsigned int, a);
    unsigned int ub = __builtin_bit_cast(unsigned int, b);
    unsigned int ud;
    asm("v_pk_max_f16 %0, %1, %2" : "=v"(ud) : "v"(ua), "v"(ub));
    return __builtin_bit_cast(__half2, ud);
}

// ---- DPP cross-lane add via compiler intrinsic (hazards handled by compiler).
template<int CTRL>
__device__ __forceinline__ float dppadd(float x) {
    int xi = __builtin_bit_cast(int, x);
    int yi = __builtin_amdgcn_update_dpp(0, xi, CTRL, 0xf, 0xf, true);
    return x + __builtin_bit_cast(float, yi);
}

// ---------------- transform GEMM: Y = half(X[N,128] @ [Wl|Wr] + bias) ----------
// Persistent, barrier-free design: W (all COLS cols) staged to LDS once per
// block; X loaded DIRECTLY global->A-fragments (32B/lane/ks, byte-efficient);
// grid-stride over 16-row tiles with depth-1 A prefetch. No recurring barriers,
// so each wave keeps its prefetch in flight -> latency-tolerant at 2 blocks/CU.
// HPL: write YL head-pair-major as [2][N][64] (for the head-split fused layer-1).
template<int COLS, bool IN_F16, bool HPL>
__global__ __launch_bounds__(256) void xform_k(
    const float* __restrict__ Xf, const __half* __restrict__ Xh,
    const float* __restrict__ Wl, const float* __restrict__ bl,
    const float* __restrict__ Wr, const float* __restrict__ br,
    __half* __restrict__ YL, __half* __restrict__ YR, int nrows)
{
    constexpr int CPW = COLS / 2;
    __shared__ _Float16 Ws[COLS * 136];

    const int t = threadIdx.x;
    // stage W (f32 -> f16, coalesced reads), layout Ws[col*136 + k]
    for (int i = t; i < 128 * COLS; i += 256) {
        int k = i / COLS, c = i % COLS;
        const float* Wp = (c >= CPW) ? Wr : Wl;
        int lc = c - ((c >= CPW) ? CPW : 0);
        Ws[c * 136 + k] = (_Float16)Wp[(long)k * CPW + lc];
    }
    __syncthreads();

    const int lane = t & 63, wv = t >> 6;
    const int m = lane & 15, quad = lane >> 4;

    // per-lane bias for col = ct*16 + m
    float bv[COLS / 16];
    #pragma unroll
    for (int ct = 0; ct < COLS / 16; ++ct) {
        int col = ct * 16 + m;
        bv[ct] = (col >= CPW) ? br[col - CPW] : bl[col];
    }

    const int ntiles = (nrows + 15) >> 4;
    const int stride = gridDim.x * 4;

    int tile = blockIdx.x * 4 + wv;
    if (tile >= ntiles) return;

    f16x8 A0[4], A1[4];

    // A-fragment load: row = tile*16 + m, k = ks*32 + quad*8 .. +8
    auto loadA = [&](int tl, f16x8* Af) {
        int row = tl * 16 + m;
        if (row >= nrows) row = nrows - 1;
        if constexpr (IN_F16) {
            const uint4* Xp = (const uint4*)(Xh + (long)row * 128);
            #pragma unroll
            for (int ks = 0; ks < 4; ++ks) {
                uint4 v = Xp[ks * 4 + quad];
                Af[ks] = __builtin_bit_cast(f16x8, v);
            }
        } else {
            const float4* Xp = (const float4*)(Xf + (long)row * 128);
            #pragma unroll
            for (int ks = 0; ks < 4; ++ks) {
                float4 a = Xp[ks * 8 + quad * 2];
                float4 b = Xp[ks * 8 + quad * 2 + 1];
                _Float16 h[8] = {(_Float16)a.x,(_Float16)a.y,(_Float16)a.z,(_Float16)a.w,
                                 (_Float16)b.x,(_Float16)b.y,(_Float16)b.z,(_Float16)b.w};
                Af[ks] = *(f16x8*)h;
            }
        }
    };

    loadA(tile, A0);

    for (; tile < ntiles; tile += stride) {
        int nt = tile + stride;
        if (nt < ntiles) loadA(nt, A1);

        const int row0 = tile * 16;
        #pragma unroll
        for (int ct = 0; ct < COLS / 16; ++ct) {
            f32x4 acc = (f32x4){0.f, 0.f, 0.f, 0.f};
            #pragma unroll
            for (int ks = 0; ks < 4; ++ks) {
                f16x8 Bf = *(const f16x8*)&Ws[(ct * 16 + m) * 136 + ks * 32 + quad * 8];
                acc = __builtin_amdgcn_mfma_f32_16x16x32_f16(A0[ks], Bf, acc, 0, 0, 0);
            }
            int col = ct * 16 + m;
            int which = col >= CPW;
            int lc = col - (which ? CPW : 0);
            _Float16* Y = (_Float16*)(which ? YR : YL);
            int rb = row0 + quad * 4;
            #pragma unroll
            for (int g = 0; g < 4; ++g) {
                int r = rb + g;
                if (r < nrows) {
                    long idx;
                    if (HPL && !which)
                        idx = (long)(lc >> 6) * ((long)nrows * 64) + (long)r * 64 + (lc & 63);
                    else
                        idx = (long)r * CPW + lc;
                    Y[idx] = (_Float16)(acc[g] + bv[ct]);
                }
            }
        }
        #pragma unroll
        for (int ks = 0; ks < 4; ++ks) A0[ks] = A1[ks];
    }
}

// ---------------- CSR build via MSD counting-sort (NO global atomics) ----------
__global__ __launch_bounds__(256) void h1_k(
    const int* __restrict__ ei, int* __restrict__ gh, int E0, int ET, int NBK)
{
    __shared__ int h[256];
    const int t = threadIdx.x, blk = blockIdx.x;
    h[t] = 0;
    __syncthreads();
    int e = blk * 4096 + t;
    #pragma unroll
    for (int u = 0; u < 16; ++u, e += 256) {
        if (e < ET) {
            int dst = (e < E0) ? ei[E0 + e] : (e - E0);
            atomicAdd(&h[dst >> 9], 1);
        }
    }
    __syncthreads();
    gh[t * NBK + blk] = h[t];
}

__global__ __launch_bounds__(256) void scan1_k(
    const int* __restrict__ cnt, int* __restrict__ loc, int* __restrict__ bsum, int n)
{
    __shared__ int wsum[4];
    int t = threadIdx.x;
    int i0 = blockIdx.x * 1024 + t * 4;
    int4 v;
    v.x = (i0 + 0 < n) ? cnt[i0 + 0] : 0;
    v.y = (i0 + 1 < n) ? cnt[i0 + 1] : 0;
    v.z = (i0 + 2 < n) ? cnt[i0 + 2] : 0;
    v.w = (i0 + 3 < n) ? cnt[i0 + 3] : 0;
    int tsum = v.x + v.y + v.z + v.w;
    int incl = tsum;
    #pragma unroll
    for (int s = 1; s < 64; s <<= 1) {
        int u = __shfl_up(incl, s, 64);
        if ((t & 63) >= s) incl += u;
    }
    int wid = t >> 6;
    if ((t & 63) == 63) wsum[wid] = incl;
    __syncthreads();
    int woff = 0;
    #pragma unroll
    for (int w = 0; w < 4; ++w) if (w < wid) woff += wsum[w];
    int ex = woff + incl - tsum;
    if (i0 + 0 < n) loc[i0 + 0] = ex;
    if (i0 + 1 < n) loc[i0 + 1] = ex + v.x;
    if (i0 + 2 < n) loc[i0 + 2] = ex + v.x + v.y;
    if (i0 + 3 < n) loc[i0 + 3] = ex + v.x + v.y + v.z;
    if (t == 255) bsum[blockIdx.x] = woff + incl;
}

__global__ void scan2_k(const int* __restrict__ bsum, int* __restrict__ bcarry,
                        int M, int* __restrict__ total_out)
{
    int lane = threadIdx.x;
    int carry = 0;
    for (int base = 0; base < M; base += 64) {
        int i = base + lane;
        int v = (i < M) ? bsum[i] : 0;
        int incl = v;
        #pragma unroll
        for (int s = 1; s < 64; s <<= 1) {
            int u = __shfl_up(incl, s, 64);
            if (lane >= s) incl += u;
        }
        if (i < M) bcarry[i] = carry + incl - v;
        carry += __shfl(incl, 63, 64);
    }
    if (lane == 0) *total_out = carry;
}

__global__ __launch_bounds__(256) void scan3_k(
    int* __restrict__ off, const int* __restrict__ bcarry, int n)
{
    int i = blockIdx.x * 256 + threadIdx.x;
    if (i >= n) return;
    off[i] += bcarry[i >> 10];
}

__global__ __launch_bounds__(256) void sc1_k(
    const int* __restrict__ ei, const int* __restrict__ gh,
    uint2* __restrict__ rec, int E0, int ET, int NBK)
{
    __shared__ int lofs[256];
    const int t = threadIdx.x, blk = blockIdx.x;
    lofs[t] = gh[t * NBK + blk];
    __syncthreads();
    int e = blk * 4096 + t;
    #pragma unroll
    for (int u = 0; u < 16; ++u, e += 256) {
        if (e < ET) {
            int src = (e < E0) ? ei[e]      : (e - E0);
            int dst = (e < E0) ? ei[E0 + e] : (e - E0);
            int p = atomicAdd(&lofs[dst >> 9], 1);
            rec[p] = make_uint2((unsigned)src, (unsigned)dst);
        }
    }
}

__global__ __launch_bounds__(256) void p2_k(
    const uint2* __restrict__ rec, const int* __restrict__ gh,
    int* __restrict__ srcs, int* __restrict__ off, int N, int NBK)
{
    __shared__ int hist[512];
    __shared__ int sc[2][512];
    __shared__ int curo[512];
    const int t = threadIdx.x;
    const int b = blockIdx.x;
    const int base = gh[b * NBK];
    const int end  = gh[(b + 1) * NBK];
    hist[t] = 0; hist[t + 256] = 0;
    __syncthreads();
    for (int i = base + t; i < end; i += 256) {
        uint2 r = rec[i];
        atomicAdd(&hist[r.y & 511], 1);
    }
    __syncthreads();
    sc[0][t] = hist[t]; sc[0][t + 256] = hist[t + 256];
    __syncthreads();
    int pp = 0;
    for (int s = 1; s < 512; s <<= 1, pp ^= 1) {
        int j0 = t, j1 = t + 256;
        sc[pp ^ 1][j0] = sc[pp][j0] + ((j0 >= s) ? sc[pp][j0 - s] : 0);
        sc[pp ^ 1][j1] = sc[pp][j1] + ((j1 >= s) ? sc[pp][j1 - s] : 0);
        __syncthreads();
    }
    {
        int j0 = t, j1 = t + 256;
        int e0 = base + sc[pp][j0] - hist[j0];
        int e1 = base + sc[pp][j1] - hist[j1];
        curo[j0] = e0;
        curo[j1] = e1;
        int d0 = b * 512 + j0, d1 = b * 512 + j1;
        if (d0 < N) off[d0] = e0;
        if (d1 < N) off[d1] = e1;
    }
    __syncthreads();
    for (int i = base + t; i < end; i += 256) {
        uint2 r = rec[i];
        int pos = atomicAdd(&curo[r.y & 511], 1);
        srcs[pos] = (int)r.x;
    }
}

// ---------------- fused score + softmax + aggregation, per dst node ----------------
// Layer 1, head-pair split: pass p handles heads {2p, 2p+1} = feats [64p, 64p+64).
template<bool RELU>
__global__ __launch_bounds__(256) void fused128hp_k(
    const __half* __restrict__ XLp, const __half* __restrict__ XR,
    const float* __restrict__ ATT, const int* __restrict__ srcs,
    const int* __restrict__ off, const float* __restrict__ bias,
    __half* __restrict__ OUT, int N, int p)
{
    const int t   = threadIdx.x;
    const int d   = blockIdx.x * 32 + (t >> 3);
    const int sub = t & 7;
    const bool nv = d < N;

    int a = 0, b = 0;
    if (nv) { a = off[d]; b = off[d + 1]; }

    __half2 xr[4] = { u2h2(0), u2h2(0), u2h2(0), u2h2(0) };
    if (nv) {
        uint4 ur = *(const uint4*)(XR + (long)d * 128 + p * 64 + sub * 8);
        xr[0] = u2h2(ur.x); xr[1] = u2h2(ur.y); xr[2] = u2h2(ur.z); xr[3] = u2h2(ur.w);
    }
    float4 at0f = ((const float4*)ATT)[p * 16 + sub * 2];
    float4 at1f = ((const float4*)ATT)[p * 16 + sub * 2 + 1];
    __half2 at[4] = { __floats2half2_rn(at0f.x, at0f.y), __floats2half2_rn(at0f.z, at0f.w),
                      __floats2half2_rn(at1f.x, at1f.y), __floats2half2_rn(at1f.z, at1f.w) };
    const __half2 neg2 = __float2half2_rn(NEG);

    float l = 0.f;
    float accv[8] = {0.f,0.f,0.f,0.f,0.f,0.f,0.f,0.f};

    const uint4* XL4 = (const uint4*)(XLp + (size_t)p * N * 64);

    if (b > a) {
        const int bm1 = b - 1;
        int sA = srcs[a];
        uint4 r0 = XL4[(long)sA * 8 + sub];
        int i1 = (a + 1 < bm1) ? a + 1 : bm1;
        int sB = srcs[i1];
        uint4 r1 = XL4[(long)sB * 8 + sub];
        int i2 = (a + 2 < bm1) ? a + 2 : bm1;
        int s2 = srcs[i2];

        for (int e = a; e < b; ++e) {
            uint4 r2 = XL4[(long)s2 * 8 + sub];
            int i3 = (e + 3 < bm1) ? e + 3 : bm1;
            int s3 = srcs[i3];

            __half2 x0 = u2h2(r0.x), x1 = u2h2(r0.y), x2 = u2h2(r0.z), x3 = u2h2(r0.w);
            __half2 s0h = __hadd2(x0, xr[0]);
            __half2 s1h = __hadd2(x1, xr[1]);
            __half2 s2h = __hadd2(x2, xr[2]);
            __half2 s3h = __hadd2(x3, xr[3]);
            __half2 q0 = hmax2(s0h, __hmul2(s0h, neg2));
            __half2 q1 = hmax2(s1h, __hmul2(s1h, neg2));
            __half2 q2 = hmax2(s2h, __hmul2(s2h, neg2));
            __half2 q3 = hmax2(s3h, __hmul2(s3h, neg2));
            float p0 = fdot2h(q0, at[0], 0.f);
            p0 = fdot2h(q1, at[1], p0);
            p0 = fdot2h(q2, at[2], p0);
            p0 = fdot2h(q3, at[3], p0);
            p0 = dppadd<0xB1>(p0);   // + lane^1
            p0 = dppadd<0x4E>(p0);   // + lane^2
            float ex = __expf(p0);
            l += ex;
            float2 f0 = __half22float2(x0), f1 = __half22float2(x1);
            float2 f2 = __half22float2(x2), f3 = __half22float2(x3);
            accv[0] += ex * f0.x; accv[1] += ex * f0.y;
            accv[2] += ex * f1.x; accv[3] += ex * f1.y;
            accv[4] += ex * f2.x; accv[5] += ex * f2.y;
            accv[6] += ex * f3.x; accv[7] += ex * f3.y;

            r0 = r1; r1 = r2; s2 = s3;
        }
    }

    if (nv) {
        float inv = 1.f / l;
        float4 b0 = ((const float4*)bias)[p * 16 + sub * 2];
        float4 b1 = ((const float4*)bias)[p * 16 + sub * 2 + 1];
        float o[8] = { accv[0]*inv + b0.x, accv[1]*inv + b0.y,
                       accv[2]*inv + b0.z, accv[3]*inv + b0.w,
                       accv[4]*inv + b1.x, accv[5]*inv + b1.y,
                       accv[6]*inv + b1.z, accv[7]*inv + b1.w };
        if constexpr (RELU) {
            #pragma unroll
            for (int j = 0; j < 8; ++j) o[j] = fmaxf(o[j], 0.f);
        }
        uint4 uo;
        uo.x = __builtin_bit_cast(unsigned int, __floats2half2_rn(o[0], o[1]));
        uo.y = __builtin_bit_cast(unsigned int, __floats2half2_rn(o[2], o[3]));
        uo.z = __builtin_bit_cast(unsigned int, __floats2half2_rn(o[4], o[5]));
        uo.w = __builtin_bit_cast(unsigned int, __floats2half2_rn(o[6], o[7]));
        *(uint4*)(OUT + (long)d * 128 + p * 64 + sub * 8) = uo;
    }
}

// Layer 2: H=1, C=64. One node per 8-lane GROUP; lane owns 8 feats.
template<bool RELU>
__global__ __launch_bounds__(256) void fused64_k(
    const __half* __restrict__ XL, const __half* __restrict__ XR,
    const float* __restrict__ ATT, const int* __restrict__ srcs,
    const int* __restrict__ off, const float* __restrict__ bias,
    float* __restrict__ OUT, int N)
{
    const int t   = threadIdx.x;
    const int d   = blockIdx.x * 32 + (t >> 3);
    const int sub = t & 7;
    const bool nv = d < N;

    int a = 0, b = 0;
    if (nv) { a = off[d]; b = off[d + 1]; }

    __half2 xr[4] = { u2h2(0), u2h2(0), u2h2(0), u2h2(0) };
    if (nv) {
        uint4 ur = *(const uint4*)(XR + (long)d * 64 + sub * 8);
        xr[0] = u2h2(ur.x); xr[1] = u2h2(ur.y); xr[2] = u2h2(ur.z); xr[3] = u2h2(ur.w);
    }
    float4 at0f = ((const float4*)ATT)[sub * 2];
    float4 at1f = ((const float4*)ATT)[sub * 2 + 1];
    __half2 at[4] = { __floats2half2_rn(at0f.x, at0f.y), __floats2half2_rn(at0f.z, at0f.w),
                      __floats2half2_rn(at1f.x, at1f.y), __floats2half2_rn(at1f.z, at1f.w) };
    const __half2 neg2 = __float2half2_rn(NEG);

    float l = 0.f;
    float accv[8] = {0.f,0.f,0.f,0.f,0.f,0.f,0.f,0.f};

    const uint4* XL4 = (const uint4*)XL;

    if (b > a) {
        const int bm1 = b - 1;
        int sA = srcs[a];
        uint4 r0 = XL4[(long)sA * 8 + sub];
        int i1 = (a + 1 < bm1) ? a + 1 : bm1;
        int sB = srcs[i1];
        uint4 r1 = XL4[(long)sB * 8 + sub];
        int i2 = (a + 2 < bm1) ? a + 2 : bm1;
        int s2 = srcs[i2];

        for (int e = a; e < b; ++e) {
            uint4 r2 = XL4[(long)s2 * 8 + sub];
            int i3 = (e + 3 < bm1) ? e + 3 : bm1;
            int s3 = srcs[i3];

            __half2 x0 = u2h2(r0.x), x1 = u2h2(r0.y), x2 = u2h2(r0.z), x3 = u2h2(r0.w);
            __half2 s0h = __hadd2(x0, xr[0]);
            __half2 s1h = __hadd2(x1, xr[1]);
            __half2 s2h = __hadd2(x2, xr[2]);
            __half2 s3h = __hadd2(x3, xr[3]);
            __half2 q0 = hmax2(s0h, __hmul2(s0h, neg2));
            __half2 q1 = hmax2(s1h, __hmul2(s1h, neg2));
            __half2 q2 = hmax2(s2h, __hmul2(s2h, neg2));
            __half2 q3 = hmax2(s3h, __hmul2(s3h, neg2));
            float p0 = fdot2h(q0, at[0], 0.f);
            p0 = fdot2h(q1, at[1], p0);
            p0 = fdot2h(q2, at[2], p0);
            p0 = fdot2h(q3, at[3], p0);
            p0 = dppadd<0xB1>(p0);
            p0 = dppadd<0x4E>(p0);
            p0 = dppadd<0x141>(p0);
            float ex = __expf(p0);
            l += ex;
            float2 f0 = __half22float2(x0), f1 = __half22float2(x1);
            float2 f2 = __half22float2(x2), f3 = __half22float2(x3);
            accv[0] += ex * f0.x; accv[1] += ex * f0.y;
            accv[2] += ex * f1.x; accv[3] += ex * f1.y;
            accv[4] += ex * f2.x; accv[5] += ex * f2.y;
            accv[6] += ex * f3.x; accv[7] += ex * f3.y;

            r0 = r1; r1 = r2; s2 = s3;
        }
    }

    if (nv) {
        float inv = 1.f / l;
        float4 b0 = ((const float4*)bias)[sub * 2];
        float4 b1 = ((const float4*)bias)[sub * 2 + 1];
        float4 o0 = make_float4(accv[0]*inv + b0.x, accv[1]*inv + b0.y,
                                accv[2]*inv + b0.z, accv[3]*inv + b0.w);
        float4 o1 = make_float4(accv[4]*inv + b1.x, accv[5]*inv + b1.y,
                                accv[6]*inv + b1.z, accv[7]*inv + b1.w);
        if constexpr (RELU) {
            o0.x = fmaxf(o0.x, 0.f); o0.y = fmaxf(o0.y, 0.f);
            o0.z = fmaxf(o0.z, 0.f); o0.w = fmaxf(o0.w, 0.f);
            o1.x = fmaxf(o1.x, 0.f); o1.y = fmaxf(o1.y, 0.f);
            o1.z = fmaxf(o1.z, 0.f); o1.w = fmaxf(o1.w, 0.f);
        }
        *(float4*)(OUT + (long)d * 64 + sub * 8)     = o0;
        *(float4*)(OUT + (long)d * 64 + sub * 8 + 4) = o1;
    }
}

extern "C" void kernel_launch(void* const* d_in, const int* in_sizes, int n_in,
                              void* d_out, int out_size, void* d_ws, size_t ws_size,
                              hipStream_t stream)
{
    const float* x     = (const float*)d_in[0];
    const int*   ei    = (const int*)  d_in[1];
    const float* Wl1   = (const float*)d_in[2];
    const float* bl1   = (const float*)d_in[3];
    const float* Wr1   = (const float*)d_in[4];
    const float* br1   = (const float*)d_in[5];
    const float* att1  = (const float*)d_in[6];
    const float* bias1 = (const float*)d_in[7];
    const float* Wl2   = (const float*)d_in[8];
    const float* bl2   = (const float*)d_in[9];
    const float* Wr2   = (const float*)d_in[10];
    const float* br2   = (const float*)d_in[11];
    const float* att2  = (const float*)d_in[12];
    const float* bias2 = (const float*)d_in[13];

    const int  N  = in_sizes[0] / 128;
    const int  E0 = in_sizes[1] / 2;
    const int  ET = E0 + N;

    char* w = (char*)d_ws;
    __half* XLh = (__half*)w;                         // N*128 halfs ([2][N][64] for layer 1)
    __half* XRh = XLh + (size_t)N * 128;              // N*128 halfs
    __half* Cch = XRh + (size_t)N * 128;              // N*128 halfs
    int*    off = (int*)(Cch + (size_t)N * 128);      // N+1
    int*    srcs= off + (N + 1);                      // ET
    int*    gh  = srcs + ET;                          // 256*NBK
    // rec aliases the XLh region: consumed by p2_k before the first GEMM runs.
    uint2*  rec = (uint2*)w;                          // ET * 8B  (<= N*128*2B)
    float*  out = (float*)d_out;

    dim3 b256(256);
    const int ng32  = (N + 31) / 32;

    const int NBK   = (ET + 4095) / 4096;
    const int n1    = 256 * NBK;
    const int NB1   = (n1 + 1023) / 1024;
    const int NBUCK = (N + 511) / 512;
    int* bsum = gh + n1;                              // NB1
    int* bcar = bsum + NB1;                           // NB1

    // ---- CSR build (counting sort, no global atomics) ----
    h1_k<<<NBK, b256, 0, stream>>>(ei, gh, E0, ET, NBK);
    scan1_k<<<NB1, b256, 0, stream>>>(gh, gh, bsum, n1);
    scan2_k<<<1, 64, 0, stream>>>(bsum, bcar, NB1, off + N);   // off[N] = ET
    scan3_k<<<(n1 + 255) / 256, b256, 0, stream>>>(gh, bcar, n1);
    sc1_k<<<NBK, b256, 0, stream>>>(ei, gh, rec, E0, ET, NBK);
    p2_k<<<NBUCK, b256, 0, stream>>>(rec, gh, srcs, off, N, NBK);

    // ---- layer 1 ----
    xform_k<256, false, true><<<512, b256, 0, stream>>>(
        x, nullptr, Wl1, bl1, Wr1, br1, XLh, XRh, N);
    fused128hp_k<true><<<ng32, b256, 0, stream>>>(XLh, XRh, att1, srcs, off, bias1, Cch, N, 0);
    fused128hp_k<true><<<ng32, b256, 0, stream>>>(XLh, XRh, att1, srcs, off, bias1, Cch, N, 1);

    // ---- layer 2 ----
    xform_k<128, true, false><<<1024, b256, 0, stream>>>(
        nullptr, Cch, Wl2, bl2, Wr2, br2, XLh, XRh, N);
    fused64_k<false><<<ng32, b256, 0, stream>>>(XLh, XRh, att2, srcs, off, bias2, out, N);
}